// Round 1
// baseline (4166.352 us; speedup 1.0000x reference)
//
#include <hip/hip_runtime.h>
#include <hip/hip_bf16.h>

#define B_ 8
#define N_ 4096
#define E_ 131072
#define D_ 64
#define H_ 128

typedef unsigned int u32;

__device__ __forceinline__ float bfbits(u32 x) { return __uint_as_float(x); }
__device__ __forceinline__ unsigned short f2bf(float f) {
  u32 x = __float_as_uint(f);
  x += 0x7fffu + ((x >> 16) & 1u);
  return (unsigned short)(x >> 16);
}
__device__ __forceinline__ float silu_f(float x) { return x / (1.0f + __expf(-x)); }

// ---------------------------------------------------------------------------
// Edge kernel: one wave (64 lanes) per (batch, edge).
//   msg_in[129] = [nf[src](64) | nf[dst](64) | dist]
//   h = silu(msg_in @ Wm1 + bm1)            (lane j -> units 2j, 2j+1)
//   m = h @ Wm2 + bm2                        -> atomicAdd into agg[b][dst][:]
//   c = silu(m @ Wc1 + bc1); w = c @ Wc2 + bc2 (wave reduce)
//   coord_delta[b][dst][:] += w * edge_vec_n
// Weights staged once per block in LDS as bf16 (f32 accumulate).
// ---------------------------------------------------------------------------
__global__ __launch_bounds__(512, 2) void egnn_edge(
    const float* __restrict__ nf, const float* __restrict__ coords,
    const int* __restrict__ ei,
    const float* __restrict__ Wm1, const float* __restrict__ bm1,
    const float* __restrict__ Wm2, const float* __restrict__ bm2,
    const float* __restrict__ Wc1, const float* __restrict__ bc1,
    const float* __restrict__ Wc2, const float* __restrict__ bc2,
    float* __restrict__ agg, float* __restrict__ cdelta)
{
  __shared__ unsigned short sWm1[129 * H_];   // 33024 B
  __shared__ unsigned short sWm2[H_ * H_];    // 32768 B
  __shared__ unsigned short sWc1[H_ * H_];    // 32768 B
  // sb: [0:128)=bm1 [128:256)=bm2 [256:384)=bc1 [384:512)=Wc2 [512]=bc2
  __shared__ float sb[513];
  __shared__ float swork[8][392];             // per-wave: msgin[0:129) h[136:264) m[264:392)

  const int tid = threadIdx.x;
  for (int i = tid; i < 129 * H_; i += 512) sWm1[i] = f2bf(Wm1[i]);
  for (int i = tid; i < H_ * H_; i += 512) sWm2[i] = f2bf(Wm2[i]);
  for (int i = tid; i < H_ * H_; i += 512) sWc1[i] = f2bf(Wc1[i]);
  if (tid < 128) {
    sb[tid] = bm1[tid];
    sb[128 + tid] = bm2[tid];
    sb[256 + tid] = bc1[tid];
    sb[384 + tid] = Wc2[tid];
  }
  if (tid == 0) sb[512] = bc2[0];
  __syncthreads();

  const int wave = tid >> 6;
  const int lane = tid & 63;
  float* W = swork[wave];
  const float bc2v = sb[512];

  const int HOFF = 136, MOFF = 264;
  const int total = B_ * E_;
  const int stride = gridDim.x * 8;

  for (int task = blockIdx.x * 8 + wave; task < total; task += stride) {
    const int e = task & (E_ - 1);
    const int b = task >> 17;
    const int src = ei[e];
    const int dst = ei[E_ + e];

    const float* nfs = nf + (size_t)(b * N_ + src) * D_;
    const float* nfd = nf + (size_t)(b * N_ + dst) * D_;
    W[lane] = nfs[lane];
    W[64 + lane] = nfd[lane];
    const float* cs = coords + (size_t)(b * N_ + src) * 3;
    const float* cd = coords + (size_t)(b * N_ + dst) * 3;
    const float d0 = cd[0] - cs[0], d1 = cd[1] - cs[1], d2 = cd[2] - cs[2];
    const float dist = sqrtf(fmaf(d0, d0, fmaf(d1, d1, d2 * d2)));
    if (lane == 0) W[128] = dist;
    __syncthreads();

    // ---- P1: msg_in @ Wm1 -> h ----
    {
      const unsigned short* wp = sWm1 + 2 * lane;
      float a0 = 0.f, a1 = 0.f, a2 = 0.f, a3 = 0.f;
#pragma unroll 8
      for (int k = 0; k < 128; k += 2) {
        float2 x = *(const float2*)&W[k];
        u32 p0 = *(const u32*)(wp + k * H_);
        u32 p1 = *(const u32*)(wp + (k + 1) * H_);
        a0 = fmaf(x.x, bfbits(p0 << 16), a0);
        a1 = fmaf(x.x, bfbits(p0 & 0xffff0000u), a1);
        a2 = fmaf(x.y, bfbits(p1 << 16), a2);
        a3 = fmaf(x.y, bfbits(p1 & 0xffff0000u), a3);
      }
      {
        float x = W[128];
        u32 p = *(const u32*)(wp + 128 * H_);
        a0 = fmaf(x, bfbits(p << 16), a0);
        a1 = fmaf(x, bfbits(p & 0xffff0000u), a1);
      }
      float h0 = silu_f(a0 + a2 + sb[2 * lane]);
      float h1 = silu_f(a1 + a3 + sb[2 * lane + 1]);
      ((float2*)(W + HOFF))[lane] = make_float2(h0, h1);
    }
    __syncthreads();

    // ---- P2: h @ Wm2 -> m, scatter to agg ----
    float m0, m1;
    {
      const unsigned short* wp = sWm2 + 2 * lane;
      float a0 = 0.f, a1 = 0.f, a2 = 0.f, a3 = 0.f;
#pragma unroll 8
      for (int k = 0; k < 128; k += 2) {
        float2 x = *(const float2*)&W[HOFF + k];
        u32 p0 = *(const u32*)(wp + k * H_);
        u32 p1 = *(const u32*)(wp + (k + 1) * H_);
        a0 = fmaf(x.x, bfbits(p0 << 16), a0);
        a1 = fmaf(x.x, bfbits(p0 & 0xffff0000u), a1);
        a2 = fmaf(x.y, bfbits(p1 << 16), a2);
        a3 = fmaf(x.y, bfbits(p1 & 0xffff0000u), a3);
      }
      m0 = a0 + a2 + sb[128 + 2 * lane];
      m1 = a1 + a3 + sb[128 + 2 * lane + 1];
      float* aggp = agg + (size_t)(b * N_ + dst) * H_;
      unsafeAtomicAdd(aggp + 2 * lane, m0);
      unsafeAtomicAdd(aggp + 2 * lane + 1, m1);
      ((float2*)(W + MOFF))[lane] = make_float2(m0, m1);
    }
    __syncthreads();

    // ---- P3: m @ Wc1 -> c, scalar w, scatter coord delta ----
    {
      const unsigned short* wp = sWc1 + 2 * lane;
      float a0 = 0.f, a1 = 0.f, a2 = 0.f, a3 = 0.f;
#pragma unroll 8
      for (int k = 0; k < 128; k += 2) {
        float2 x = *(const float2*)&W[MOFF + k];
        u32 p0 = *(const u32*)(wp + k * H_);
        u32 p1 = *(const u32*)(wp + (k + 1) * H_);
        a0 = fmaf(x.x, bfbits(p0 << 16), a0);
        a1 = fmaf(x.x, bfbits(p0 & 0xffff0000u), a1);
        a2 = fmaf(x.y, bfbits(p1 << 16), a2);
        a3 = fmaf(x.y, bfbits(p1 & 0xffff0000u), a3);
      }
      float c0 = silu_f(a0 + a2 + sb[256 + 2 * lane]);
      float c1 = silu_f(a1 + a3 + sb[256 + 2 * lane + 1]);
      float v = fmaf(c0, sb[384 + 2 * lane], c1 * sb[384 + 2 * lane + 1]);
      v += __shfl_xor(v, 1);
      v += __shfl_xor(v, 2);
      v += __shfl_xor(v, 4);
      v += __shfl_xor(v, 8);
      v += __shfl_xor(v, 16);
      v += __shfl_xor(v, 32);
      const float wcoef = v + bc2v;
      if (lane < 3) {
        const float ev = (lane == 0 ? d0 : (lane == 1 ? d1 : d2)) / (dist + 1e-8f);
        unsafeAtomicAdd(cdelta + (size_t)(b * N_ + dst) * 3 + lane, wcoef * ev);
      }
    }
    // no barrier needed: next stage only overwrites msg_in region, whose last
    // read (P1) is separated by two barriers above.
  }
}

// ---------------------------------------------------------------------------
// Node kernel: one wave per (batch, node).
//   in[192] = [nf(64) | agg(128)]; h = silu(in @ Wn1 + bn1)
//   nf_new = nf + h @ Wn2 + bn2 ; coords_new = coords + cdelta
// ---------------------------------------------------------------------------
__global__ __launch_bounds__(512, 2) void egnn_node(
    const float* __restrict__ nf, const float* __restrict__ coords,
    const float* __restrict__ agg, const float* __restrict__ cdelta,
    const float* __restrict__ Wn1, const float* __restrict__ bn1,
    const float* __restrict__ Wn2, const float* __restrict__ bn2,
    float* __restrict__ out_nf, float* __restrict__ out_c)
{
  __shared__ unsigned short sWn1[192 * H_];   // 49152 B
  __shared__ unsigned short sWn2[H_ * D_];    // 16384 B
  __shared__ float sb[192];                   // bn1[0:128) bn2[128:192)
  __shared__ float swork[8][328];             // per-wave: in[0:192) h[192:320)

  const int tid = threadIdx.x;
  for (int i = tid; i < 192 * H_; i += 512) sWn1[i] = f2bf(Wn1[i]);
  for (int i = tid; i < H_ * D_; i += 512) sWn2[i] = f2bf(Wn2[i]);
  if (tid < 128) sb[tid] = bn1[tid];
  if (tid >= 128 && tid < 192) sb[tid] = bn2[tid - 128];
  __syncthreads();

  const int wave = tid >> 6;
  const int lane = tid & 63;
  float* W = swork[wave];

  const int total = B_ * N_;
  const int stride = gridDim.x * 8;

  for (int task = blockIdx.x * 8 + wave; task < total; task += stride) {
    const float* nfp = nf + (size_t)task * D_;
    const float* ap = agg + (size_t)task * H_;
    W[lane] = nfp[lane];
    W[64 + lane] = ap[lane];
    W[128 + lane] = ap[64 + lane];
    __syncthreads();

    // P1: in @ Wn1 -> h (units 2*lane, 2*lane+1)
    {
      const unsigned short* wp = sWn1 + 2 * lane;
      float a0 = 0.f, a1 = 0.f, a2 = 0.f, a3 = 0.f;
#pragma unroll 8
      for (int k = 0; k < 192; k += 2) {
        float2 x = *(const float2*)&W[k];
        u32 p0 = *(const u32*)(wp + k * H_);
        u32 p1 = *(const u32*)(wp + (k + 1) * H_);
        a0 = fmaf(x.x, bfbits(p0 << 16), a0);
        a1 = fmaf(x.x, bfbits(p0 & 0xffff0000u), a1);
        a2 = fmaf(x.y, bfbits(p1 << 16), a2);
        a3 = fmaf(x.y, bfbits(p1 & 0xffff0000u), a3);
      }
      float h0 = silu_f(a0 + a2 + sb[2 * lane]);
      float h1 = silu_f(a1 + a3 + sb[2 * lane + 1]);
      ((float2*)(W + 192))[lane] = make_float2(h0, h1);
    }
    __syncthreads();

    // P2: h @ Wn2 -> out unit = lane (64 units)
    {
      float a0 = 0.f, a1 = 0.f, a2 = 0.f, a3 = 0.f;
#pragma unroll 8
      for (int k = 0; k < 128; k += 4) {
        float2 xa = *(const float2*)&W[192 + k];
        float2 xb = *(const float2*)&W[192 + k + 2];
        a0 = fmaf(xa.x, bfbits(((u32)sWn2[(k + 0) * D_ + lane]) << 16), a0);
        a1 = fmaf(xa.y, bfbits(((u32)sWn2[(k + 1) * D_ + lane]) << 16), a1);
        a2 = fmaf(xb.x, bfbits(((u32)sWn2[(k + 2) * D_ + lane]) << 16), a2);
        a3 = fmaf(xb.y, bfbits(((u32)sWn2[(k + 3) * D_ + lane]) << 16), a3);
      }
      out_nf[(size_t)task * D_ + lane] =
          nfp[lane] + (a0 + a1 + a2 + a3) + sb[128 + lane];
      if (lane < 3) {
        out_c[(size_t)task * 3 + lane] =
            coords[(size_t)task * 3 + lane] + cdelta[(size_t)task * 3 + lane];
      }
    }
    __syncthreads();   // protect in[] region before next stage overwrite
  }
}

extern "C" void kernel_launch(void* const* d_in, const int* in_sizes, int n_in,
                              void* d_out, int out_size, void* d_ws, size_t ws_size,
                              hipStream_t stream) {
  const float* nf     = (const float*)d_in[0];
  const float* coords = (const float*)d_in[1];
  const int*   ei     = (const int*)d_in[2];
  const float* Wm1 = (const float*)d_in[3];
  const float* bm1 = (const float*)d_in[4];
  const float* Wm2 = (const float*)d_in[5];
  const float* bm2 = (const float*)d_in[6];
  const float* Wn1 = (const float*)d_in[7];
  const float* bn1 = (const float*)d_in[8];
  const float* Wn2 = (const float*)d_in[9];
  const float* bn2 = (const float*)d_in[10];
  const float* Wc1 = (const float*)d_in[11];
  const float* bc1 = (const float*)d_in[12];
  const float* Wc2 = (const float*)d_in[13];
  const float* bc2 = (const float*)d_in[14];

  float* agg    = (float*)d_ws;                       // [B,N,128] f32
  float* cdelta = agg + (size_t)B_ * N_ * H_;         // [B,N,3]   f32
  float* out_nf = (float*)d_out;                      // [B,N,64]
  float* out_c  = out_nf + (size_t)B_ * N_ * D_;      // [B,N,3]

  const size_t zero_bytes =
      ((size_t)B_ * N_ * H_ + (size_t)B_ * N_ * 3) * sizeof(float);
  hipMemsetAsync(d_ws, 0, zero_bytes, stream);

  egnn_edge<<<512, 512, 0, stream>>>(nf, coords, ei, Wm1, bm1, Wm2, bm2,
                                     Wc1, bc1, Wc2, bc2, agg, cdelta);
  egnn_node<<<512, 512, 0, stream>>>(nf, coords, agg, cdelta,
                                     Wn1, bn1, Wn2, bn2, out_nf, out_c);
}

// Round 2
// 708.285 us; speedup vs baseline: 5.8823x; 5.8823x over previous
//
#include <hip/hip_runtime.h>
#include <hip/hip_bf16.h>

#define B_ 8
#define N_ 4096
#define E_ 131072
#define D_ 64
#define H_ 128

#define TILES_TOTAL ((B_ * E_) / 64)          // 16384 tiles of 64 edges
#define EDGE_BLOCKS 512
#define TILES_PER_BLOCK (TILES_TOTAL / EDGE_BLOCKS)  // 32

typedef unsigned int u32;
typedef short bf16x8 __attribute__((ext_vector_type(8)));
typedef float f32x4 __attribute__((ext_vector_type(4)));

__device__ __forceinline__ unsigned short f2bf(float f) {
  u32 x = __float_as_uint(f);
  x += 0x7fffu + ((x >> 16) & 1u);   // RNE
  return (unsigned short)(x >> 16);
}
__device__ __forceinline__ float silu_f(float x) { return x / (1.0f + __expf(-x)); }

// XOR-swizzled u16 index into a [rows][128] bf16 LDS tile (row stride 256 B).
// Flips 16B-granule bits with row&7 -> conflict-free ds_read_b128 column slices.
__device__ __forceinline__ int swz(int row, int col) {
  return row * 128 + (col ^ ((row & 7) << 3));
}

__device__ __forceinline__ void store4(unsigned short* buf, int row, int col, float4 v) {
  u32 p0 = (u32)f2bf(v.x) | ((u32)f2bf(v.y) << 16);
  u32 p1 = (u32)f2bf(v.z) | ((u32)f2bf(v.w) << 16);
  *(uint2*)&buf[swz(row, col)] = make_uint2(p0, p1);  // col%4==0 -> 8B aligned
}

// 64x128 (M x N) GEMM over K=128: in[64][128] (rows=edges) x wT[128][128] (rows=n).
// Wave computes 2x2 16x16 tiles at (rA base rows, rB base cols).
__device__ __forceinline__ void gemm128(const unsigned short* in,
                                        const unsigned short* wT,
                                        int rA, int rB, int k0l, f32x4 acc[2][2]) {
#pragma unroll
  for (int ks = 0; ks < 4; ++ks) {
    const int k = ks * 32 + k0l;
    bf16x8 a0 = *(const bf16x8*)&in[swz(rA, k)];
    bf16x8 a1 = *(const bf16x8*)&in[swz(rA + 16, k)];
    bf16x8 b0 = *(const bf16x8*)&wT[swz(rB, k)];
    bf16x8 b1 = *(const bf16x8*)&wT[swz(rB + 16, k)];
    acc[0][0] = __builtin_amdgcn_mfma_f32_16x16x32_bf16(a0, b0, acc[0][0], 0, 0, 0);
    acc[0][1] = __builtin_amdgcn_mfma_f32_16x16x32_bf16(a0, b1, acc[0][1], 0, 0, 0);
    acc[1][0] = __builtin_amdgcn_mfma_f32_16x16x32_bf16(a1, b0, acc[1][0], 0, 0, 0);
    acc[1][1] = __builtin_amdgcn_mfma_f32_16x16x32_bf16(a1, b1, acc[1][1], 0, 0, 0);
  }
}

__global__ __launch_bounds__(512, 1) void egnn_edge_mfma(
    const float* __restrict__ nf, const float* __restrict__ coords,
    const int* __restrict__ ei,
    const float* __restrict__ Wm1, const float* __restrict__ bm1,
    const float* __restrict__ Wm2, const float* __restrict__ bm2,
    const float* __restrict__ Wc1, const float* __restrict__ bc1,
    const float* __restrict__ Wc2, const float* __restrict__ bc2,
    float* __restrict__ agg, float* __restrict__ cdelta)
{
  __shared__ unsigned short sW1[128 * 128];   // Wm1[0:128]^T swizzled, 32 KB
  __shared__ unsigned short sW2[128 * 128];   // Wm2^T
  __shared__ unsigned short sW3[128 * 128];   // Wc1^T
  __shared__ unsigned short smsg[64 * 128];   // msg_in tile (cols 0..127), 16 KB
  __shared__ unsigned short shh[64 * 128];    // h tile
  __shared__ unsigned short smm[64 * 128];    // m tile (bf16 copy for L3)
  __shared__ float sb[513];        // bm1|bm2|bc1|Wc2|bc2
  __shared__ float sW1r128[128];   // Wm1 row 128 (dist) f32
  __shared__ float4 sgeo[64];      // d0,d1,d2,dist
  __shared__ int sdst[64];
  __shared__ float swpart[4][64];  // per-colgroup row partials of coord scalar

  const int tid = threadIdx.x;
  for (int i = tid; i < 128 * 128; i += 512) {
    const int k = i >> 7, n = i & 127;
    const int d = swz(n, k);
    sW1[d] = f2bf(Wm1[i]);
    sW2[d] = f2bf(Wm2[i]);
    sW3[d] = f2bf(Wc1[i]);
  }
  if (tid < 128) {
    sW1r128[tid] = Wm1[128 * 128 + tid];
    sb[tid] = bm1[tid];
    sb[128 + tid] = bm2[tid];
    sb[256 + tid] = bc1[tid];
    sb[384 + tid] = Wc2[tid];
  }
  if (tid == 0) sb[512] = bc2[0];
  __syncthreads();

  const int lane = tid & 63;
  const int w = tid >> 6;
  const int l15 = lane & 15;
  const int l4 = lane >> 4;
  const int k0l = l4 * 8;
  const int rowbase = (w >> 2) * 32;   // waves 0-3: rows 0-31; 4-7: rows 32-63
  const int colbase = (w & 3) * 32;    // col pair group
  const int rA = rowbase + l15;
  const int rB = colbase + l15;
  const int n0 = colbase + l15;
  const int n1 = n0 + 16;
  const float bc2v = sb[512];
  const int m_t = tid >> 3;            // gather: 8 threads per edge row
  const int q_t = tid & 7;

  for (int t = 0; t < TILES_PER_BLOCK; ++t) {
    const int tile = blockIdx.x * TILES_PER_BLOCK + t;
    const int b = tile >> 11;                 // 2048 tiles per batch
    const int ebase = (tile & 2047) * 64;

    // ---- gather: geometry (wave 0) + msg_in rows (all waves) ----
    if (tid < 64) {
      const int e = ebase + tid;
      const int s = ei[e];
      const int d = ei[E_ + e];
      sdst[tid] = d;
      const float* cs = coords + (size_t)(b * N_ + s) * 3;
      const float* cd = coords + (size_t)(b * N_ + d) * 3;
      const float d0 = cd[0] - cs[0], d1 = cd[1] - cs[1], d2 = cd[2] - cs[2];
      const float dist = sqrtf(fmaf(d0, d0, fmaf(d1, d1, d2 * d2)));
      sgeo[tid] = make_float4(d0, d1, d2, dist);
    }
    {
      const int e = ebase + m_t;
      const int s = ei[e];
      const int d = ei[E_ + e];
      const float4* ps = (const float4*)(nf + (size_t)(b * N_ + s) * 64);
      const float4* pd = (const float4*)(nf + (size_t)(b * N_ + d) * 64);
      float4 v0 = ps[q_t], v1 = ps[q_t + 8];
      float4 v2 = pd[q_t], v3 = pd[q_t + 8];
      store4(smsg, m_t, 4 * q_t, v0);
      store4(smsg, m_t, 32 + 4 * q_t, v1);
      store4(smsg, m_t, 64 + 4 * q_t, v2);
      store4(smsg, m_t, 96 + 4 * q_t, v3);
    }
    __syncthreads();

    // ---- L1: h = silu(msg @ Wm1 + bm1)  (+ dist rank-1 term) ----
    f32x4 acc[2][2];
    {
      f32x4 z = {0.f, 0.f, 0.f, 0.f};
      acc[0][0] = z; acc[0][1] = z; acc[1][0] = z; acc[1][1] = z;
    }
    gemm128(smsg, sW1, rA, rB, k0l, acc);
    {
      const float bb0 = sb[n0], bb1 = sb[n1];
      const float w0 = sW1r128[n0], w1 = sW1r128[n1];
#pragma unroll
      for (int i = 0; i < 2; ++i)
#pragma unroll
        for (int r = 0; r < 4; ++r) {
          const int m = rowbase + 16 * i + l4 * 4 + r;
          const float dist = sgeo[m].w;
          shh[swz(m, n0)] = f2bf(silu_f(acc[i][0][r] + bb0 + dist * w0));
          shh[swz(m, n1)] = f2bf(silu_f(acc[i][1][r] + bb1 + dist * w1));
        }
    }
    __syncthreads();

    // ---- L2: m = h @ Wm2 + bm2 -> atomics into agg + bf16 copy for L3 ----
    {
      f32x4 z = {0.f, 0.f, 0.f, 0.f};
      acc[0][0] = z; acc[0][1] = z; acc[1][0] = z; acc[1][1] = z;
    }
    gemm128(shh, sW2, rA, rB, k0l, acc);
    {
      const float bb0 = sb[128 + n0], bb1 = sb[128 + n1];
#pragma unroll
      for (int i = 0; i < 2; ++i)
#pragma unroll
        for (int r = 0; r < 4; ++r) {
          const int m = rowbase + 16 * i + l4 * 4 + r;
          float* base = agg + ((size_t)(b * N_ + sdst[m])) * H_;
          const float v0 = acc[i][0][r] + bb0;
          const float v1 = acc[i][1][r] + bb1;
          unsafeAtomicAdd(base + n0, v0);
          unsafeAtomicAdd(base + n1, v1);
          smm[swz(m, n0)] = f2bf(v0);
          smm[swz(m, n1)] = f2bf(v1);
        }
    }
    __syncthreads();

    // ---- L3: c = silu(m @ Wc1 + bc1); w = c . Wc2 (row reduce) ----
    {
      f32x4 z = {0.f, 0.f, 0.f, 0.f};
      acc[0][0] = z; acc[0][1] = z; acc[1][0] = z; acc[1][1] = z;
    }
    gemm128(smm, sW3, rA, rB, k0l, acc);
    {
      const float bb0 = sb[256 + n0], bb1 = sb[256 + n1];
      const float c0 = sb[384 + n0], c1 = sb[384 + n1];
#pragma unroll
      for (int i = 0; i < 2; ++i)
#pragma unroll
        for (int r = 0; r < 4; ++r) {
          float p = silu_f(acc[i][0][r] + bb0) * c0 + silu_f(acc[i][1][r] + bb1) * c1;
          p += __shfl_xor(p, 1);
          p += __shfl_xor(p, 2);
          p += __shfl_xor(p, 4);
          p += __shfl_xor(p, 8);
          if (l15 == 0) swpart[w & 3][rowbase + 16 * i + l4 * 4 + r] = p;
        }
    }
    __syncthreads();

    // ---- coord scatter (wave 0) ----
    if (tid < 64) {
      float wc = bc2v;
#pragma unroll
      for (int cg = 0; cg < 4; ++cg) wc += swpart[cg][tid];
      const float4 g = sgeo[tid];
      const float inv = 1.0f / (g.w + 1e-8f);
      float* base = cdelta + ((size_t)(b * N_ + sdst[tid])) * 3;
      unsafeAtomicAdd(base + 0, wc * g.x * inv);
      unsafeAtomicAdd(base + 1, wc * g.y * inv);
      unsafeAtomicAdd(base + 2, wc * g.z * inv);
    }
    // next-tile gather writes (sdst/sgeo by wave 0 after its atomics; smsg last
    // read 3 barriers ago) are race-free; swpart rewritten only after 3 barriers.
  }
}

// ---------------------------------------------------------------------------
// Node kernel (unchanged from R1): one wave per (batch,node), VALU dot products.
// ---------------------------------------------------------------------------
__device__ __forceinline__ float bfbits(u32 x) { return __uint_as_float(x); }

__global__ __launch_bounds__(512, 2) void egnn_node(
    const float* __restrict__ nf, const float* __restrict__ coords,
    const float* __restrict__ agg, const float* __restrict__ cdelta,
    const float* __restrict__ Wn1, const float* __restrict__ bn1,
    const float* __restrict__ Wn2, const float* __restrict__ bn2,
    float* __restrict__ out_nf, float* __restrict__ out_c)
{
  __shared__ unsigned short sWn1[192 * H_];
  __shared__ unsigned short sWn2[H_ * D_];
  __shared__ float sb[192];
  __shared__ float swork[8][328];

  const int tid = threadIdx.x;
  for (int i = tid; i < 192 * H_; i += 512) sWn1[i] = f2bf(Wn1[i]);
  for (int i = tid; i < H_ * D_; i += 512) sWn2[i] = f2bf(Wn2[i]);
  if (tid < 128) sb[tid] = bn1[tid];
  if (tid >= 128 && tid < 192) sb[tid] = bn2[tid - 128];
  __syncthreads();

  const int wave = tid >> 6;
  const int lane = tid & 63;
  float* W = swork[wave];

  const int total = B_ * N_;
  const int stride = gridDim.x * 8;

  for (int task = blockIdx.x * 8 + wave; task < total; task += stride) {
    const float* nfp = nf + (size_t)task * D_;
    const float* ap = agg + (size_t)task * H_;
    W[lane] = nfp[lane];
    W[64 + lane] = ap[lane];
    W[128 + lane] = ap[64 + lane];
    __syncthreads();

    {
      const unsigned short* wp = sWn1 + 2 * lane;
      float a0 = 0.f, a1 = 0.f, a2 = 0.f, a3 = 0.f;
#pragma unroll 8
      for (int k = 0; k < 192; k += 2) {
        float2 x = *(const float2*)&W[k];
        u32 p0 = *(const u32*)(wp + k * H_);
        u32 p1 = *(const u32*)(wp + (k + 1) * H_);
        a0 = fmaf(x.x, bfbits(p0 << 16), a0);
        a1 = fmaf(x.x, bfbits(p0 & 0xffff0000u), a1);
        a2 = fmaf(x.y, bfbits(p1 << 16), a2);
        a3 = fmaf(x.y, bfbits(p1 & 0xffff0000u), a3);
      }
      float h0 = silu_f(a0 + a2 + sb[2 * lane]);
      float h1 = silu_f(a1 + a3 + sb[2 * lane + 1]);
      ((float2*)(W + 192))[lane] = make_float2(h0, h1);
    }
    __syncthreads();

    {
      float a0 = 0.f, a1 = 0.f, a2 = 0.f, a3 = 0.f;
#pragma unroll 8
      for (int k = 0; k < 128; k += 4) {
        float2 xa = *(const float2*)&W[192 + k];
        float2 xb = *(const float2*)&W[192 + k + 2];
        a0 = fmaf(xa.x, bfbits(((u32)sWn2[(k + 0) * D_ + lane]) << 16), a0);
        a1 = fmaf(xa.y, bfbits(((u32)sWn2[(k + 1) * D_ + lane]) << 16), a1);
        a2 = fmaf(xb.x, bfbits(((u32)sWn2[(k + 2) * D_ + lane]) << 16), a2);
        a3 = fmaf(xb.y, bfbits(((u32)sWn2[(k + 3) * D_ + lane]) << 16), a3);
      }
      out_nf[(size_t)task * D_ + lane] =
          nfp[lane] + (a0 + a1 + a2 + a3) + sb[128 + lane];
      if (lane < 3) {
        out_c[(size_t)task * 3 + lane] =
            coords[(size_t)task * 3 + lane] + cdelta[(size_t)task * 3 + lane];
      }
    }
    __syncthreads();
  }
}

extern "C" void kernel_launch(void* const* d_in, const int* in_sizes, int n_in,
                              void* d_out, int out_size, void* d_ws, size_t ws_size,
                              hipStream_t stream) {
  const float* nf     = (const float*)d_in[0];
  const float* coords = (const float*)d_in[1];
  const int*   ei     = (const int*)d_in[2];
  const float* Wm1 = (const float*)d_in[3];
  const float* bm1 = (const float*)d_in[4];
  const float* Wm2 = (const float*)d_in[5];
  const float* bm2 = (const float*)d_in[6];
  const float* Wn1 = (const float*)d_in[7];
  const float* bn1 = (const float*)d_in[8];
  const float* Wn2 = (const float*)d_in[9];
  const float* bn2 = (const float*)d_in[10];
  const float* Wc1 = (const float*)d_in[11];
  const float* bc1 = (const float*)d_in[12];
  const float* Wc2 = (const float*)d_in[13];
  const float* bc2 = (const float*)d_in[14];

  float* agg    = (float*)d_ws;                       // [B,N,128] f32
  float* cdelta = agg + (size_t)B_ * N_ * H_;         // [B,N,3]   f32
  float* out_nf = (float*)d_out;                      // [B,N,64]
  float* out_c  = out_nf + (size_t)B_ * N_ * D_;      // [B,N,3]

  const size_t zero_bytes =
      ((size_t)B_ * N_ * H_ + (size_t)B_ * N_ * 3) * sizeof(float);
  hipMemsetAsync(d_ws, 0, zero_bytes, stream);

  egnn_edge_mfma<<<EDGE_BLOCKS, 512, 0, stream>>>(
      nf, coords, ei, Wm1, bm1, Wm2, bm2, Wc1, bc1, Wc2, bc2, agg, cdelta);
  egnn_node<<<512, 512, 0, stream>>>(nf, coords, agg, cdelta,
                                     Wn1, bn1, Wn2, bn2, out_nf, out_c);
}

// Round 3
// 593.713 us; speedup vs baseline: 7.0175x; 1.1930x over previous
//
#include <hip/hip_runtime.h>
#include <hip/hip_bf16.h>

#define B_ 8
#define N_ 4096
#define E_ 131072
#define D_ 64
#define H_ 128

#define EDGE_BLOCKS 256
#define TILES_TOTAL ((B_ * E_) / 64)                  // 16384 tiles of 64 edges
#define TILES_PER_BLOCK (TILES_TOTAL / EDGE_BLOCKS)   // 64

typedef unsigned int u32;
typedef short bf16x8 __attribute__((ext_vector_type(8)));
typedef float f32x4 __attribute__((ext_vector_type(4)));

__device__ __forceinline__ unsigned short f2bf(float f) {
  u32 x = __float_as_uint(f);
  x += 0x7fffu + ((x >> 16) & 1u);   // RNE
  return (unsigned short)(x >> 16);
}
__device__ __forceinline__ float bf2f(unsigned short v) {
  return __uint_as_float(((u32)v) << 16);
}
__device__ __forceinline__ float silu_f(float x) { return x / (1.0f + __expf(-x)); }

// XOR-swizzled u16 index into a [rows][128] bf16 LDS tile (row stride 256 B).
__device__ __forceinline__ int swz(int row, int col) {
  return row * 128 + (col ^ ((row & 7) << 3));
}

__device__ __forceinline__ void store4(unsigned short* buf, int row, int col, float4 v) {
  u32 p0 = (u32)f2bf(v.x) | ((u32)f2bf(v.y) << 16);
  u32 p1 = (u32)f2bf(v.z) | ((u32)f2bf(v.w) << 16);
  *(uint2*)&buf[swz(row, col)] = make_uint2(p0, p1);
}

__device__ __forceinline__ void gemm128(const unsigned short* in,
                                        const unsigned short* wT,
                                        int rA, int rB, int k0l, f32x4 acc[2][2]) {
#pragma unroll
  for (int ks = 0; ks < 4; ++ks) {
    const int k = ks * 32 + k0l;
    bf16x8 a0 = *(const bf16x8*)&in[swz(rA, k)];
    bf16x8 a1 = *(const bf16x8*)&in[swz(rA + 16, k)];
    bf16x8 b0 = *(const bf16x8*)&wT[swz(rB, k)];
    bf16x8 b1 = *(const bf16x8*)&wT[swz(rB + 16, k)];
    acc[0][0] = __builtin_amdgcn_mfma_f32_16x16x32_bf16(a0, b0, acc[0][0], 0, 0, 0);
    acc[0][1] = __builtin_amdgcn_mfma_f32_16x16x32_bf16(a0, b1, acc[0][1], 0, 0, 0);
    acc[1][0] = __builtin_amdgcn_mfma_f32_16x16x32_bf16(a1, b0, acc[1][0], 0, 0, 0);
    acc[1][1] = __builtin_amdgcn_mfma_f32_16x16x32_bf16(a1, b1, acc[1][1], 0, 0, 0);
  }
}

// ---------------- sort-by-dst kernels ----------------
__global__ void hist_k(const int* __restrict__ ei, int* __restrict__ hist) {
  const int e = blockIdx.x * 256 + threadIdx.x;
  atomicAdd(&hist[ei[E_ + e]], 1);
}

__global__ __launch_bounds__(1024) void scan4096(int* __restrict__ h) {
  __shared__ int wsums[16];
  const int tid = threadIdx.x;
  const int lane = tid & 63, wv = tid >> 6;
  int4 v = ((int4*)h)[tid];
  const int s = v.x + v.y + v.z + v.w;
  int incl = s;
#pragma unroll
  for (int off = 1; off < 64; off <<= 1) {
    int u = __shfl_up(incl, off);
    if (lane >= off) incl += u;
  }
  if (lane == 63) wsums[wv] = incl;
  __syncthreads();
  if (wv == 0) {
    int ws = (lane < 16) ? wsums[lane] : 0;
#pragma unroll
    for (int off = 1; off < 16; off <<= 1) {
      int u = __shfl_up(ws, off);
      if (lane >= off) ws += u;
    }
    if (lane < 16) wsums[lane] = ws;
  }
  __syncthreads();
  int base = (wv ? wsums[wv - 1] : 0) + (incl - s);
  int4 o;
  o.x = base; o.y = base + v.x; o.z = o.y + v.y; o.w = o.z + v.z;
  ((int4*)h)[tid] = o;
}

__global__ void scatter_k(const int* __restrict__ ei, int* __restrict__ offs,
                          int* __restrict__ src_s, int* __restrict__ dst_s) {
  const int e = blockIdx.x * 256 + threadIdx.x;
  const int d = ei[E_ + e];
  const int p = atomicAdd(&offs[d], 1);
  src_s[p] = ei[e];
  dst_s[p] = d;
}

// ---------------- edge kernel (dst-sorted, run-reduced scatter) ----------------
__global__ __launch_bounds__(512, 1) void egnn_edge_mfma(
    const float* __restrict__ nf, const float* __restrict__ coords,
    const int* __restrict__ src_s, const int* __restrict__ dst_s,
    const float* __restrict__ Wm1, const float* __restrict__ bm1,
    const float* __restrict__ Wm2, const float* __restrict__ bm2,
    const float* __restrict__ Wc1, const float* __restrict__ bc1,
    const float* __restrict__ Wc2, const float* __restrict__ bc2,
    float* __restrict__ agg, float* __restrict__ cdelta)
{
  __shared__ unsigned short sW1[128 * 128];
  __shared__ unsigned short sW2[128 * 128];
  __shared__ unsigned short sW3[128 * 128];
  __shared__ unsigned short smsg[64 * 128];
  __shared__ unsigned short shh[64 * 128];
  __shared__ unsigned short smm[64 * 128];
  __shared__ float sb[513];        // bm1|bm2|bc1|Wc2|bc2
  __shared__ float sW1r128[128];
  __shared__ float4 sgeo[2][64];   // double-buffered (parity)
  __shared__ int sdst[2][64];
  __shared__ float swpart[4][64];

  const int tid = threadIdx.x;
  for (int i = tid; i < 128 * 128; i += 512) {
    const int k = i >> 7, n = i & 127;
    const int d = swz(n, k);
    sW1[d] = f2bf(Wm1[i]);
    sW2[d] = f2bf(Wm2[i]);
    sW3[d] = f2bf(Wc1[i]);
  }
  if (tid < 128) {
    sW1r128[tid] = Wm1[128 * 128 + tid];
    sb[tid] = bm1[tid];
    sb[128 + tid] = bm2[tid];
    sb[256 + tid] = bc1[tid];
    sb[384 + tid] = Wc2[tid];
  }
  if (tid == 0) sb[512] = bc2[0];
  __syncthreads();

  const int lane = tid & 63;
  const int w = tid >> 6;
  const int l15 = lane & 15;
  const int l4 = lane >> 4;
  const int k0l = l4 * 8;
  const int rowbase = (w >> 2) * 32;
  const int colbase = (w & 3) * 32;
  const int rA = rowbase + l15;
  const int rB = colbase + l15;
  const int n0 = colbase + l15;
  const int n1 = n0 + 16;
  const float bc2v = sb[512];
  const int m_t = tid >> 3;
  const int q_t = tid & 7;

  // batch = XCD: blocks with same blockIdx%8 land on the same XCD (round-robin)
  const int myblk = (blockIdx.x & 7) * (EDGE_BLOCKS / 8) + (blockIdx.x >> 3);
  const int b = myblk >> 5;                 // 32 blocks per batch
  const int gbase = (myblk & 31) * TILES_PER_BLOCK;

  for (int t = 0; t < TILES_PER_BLOCK; ++t) {
    const int p = t & 1;
    const int ebase = (gbase + t) * 64;     // sorted-position base

    // ---- gather ----
    if (tid < 64) {
      const int e = ebase + tid;
      const int s = src_s[e];
      const int d = dst_s[e];
      sdst[p][tid] = d;
      const float* cs = coords + (size_t)(b * N_ + s) * 3;
      const float* cd = coords + (size_t)(b * N_ + d) * 3;
      const float d0 = cd[0] - cs[0], d1 = cd[1] - cs[1], d2 = cd[2] - cs[2];
      const float dist = sqrtf(fmaf(d0, d0, fmaf(d1, d1, d2 * d2)));
      sgeo[p][tid] = make_float4(d0, d1, d2, dist);
    }
    {
      const int e = ebase + m_t;
      const int s = src_s[e];
      const int d = dst_s[e];
      const float4* ps = (const float4*)(nf + (size_t)(b * N_ + s) * 64);
      const float4* pd = (const float4*)(nf + (size_t)(b * N_ + d) * 64);
      float4 v0 = ps[q_t], v1 = ps[q_t + 8];
      float4 v2 = pd[q_t], v3 = pd[q_t + 8];
      store4(smsg, m_t, 4 * q_t, v0);
      store4(smsg, m_t, 32 + 4 * q_t, v1);
      store4(smsg, m_t, 64 + 4 * q_t, v2);
      store4(smsg, m_t, 96 + 4 * q_t, v3);
    }
    __syncthreads();   // B1

    // ---- L1: h = silu(msg @ Wm1 + bm1 + dist * Wm1[128,:]) ----
    f32x4 acc[2][2];
    {
      f32x4 z = {0.f, 0.f, 0.f, 0.f};
      acc[0][0] = z; acc[0][1] = z; acc[1][0] = z; acc[1][1] = z;
    }
    gemm128(smsg, sW1, rA, rB, k0l, acc);
    {
      const float bb0 = sb[n0], bb1 = sb[n1];
      const float w0 = sW1r128[n0], w1 = sW1r128[n1];
#pragma unroll
      for (int i = 0; i < 2; ++i)
#pragma unroll
        for (int r = 0; r < 4; ++r) {
          const int m = rowbase + 16 * i + l4 * 4 + r;
          const float dist = sgeo[p][m].w;
          shh[swz(m, n0)] = f2bf(silu_f(acc[i][0][r] + bb0 + dist * w0));
          shh[swz(m, n1)] = f2bf(silu_f(acc[i][1][r] + bb1 + dist * w1));
        }
    }
    __syncthreads();   // B2

    // ---- L2: m = h @ Wm2 + bm2 -> bf16 tile only (no atomics) ----
    {
      f32x4 z = {0.f, 0.f, 0.f, 0.f};
      acc[0][0] = z; acc[0][1] = z; acc[1][0] = z; acc[1][1] = z;
    }
    gemm128(shh, sW2, rA, rB, k0l, acc);
    {
      const float bb0 = sb[128 + n0], bb1 = sb[128 + n1];
#pragma unroll
      for (int i = 0; i < 2; ++i)
#pragma unroll
        for (int r = 0; r < 4; ++r) {
          const int m = rowbase + 16 * i + l4 * 4 + r;
          smm[swz(m, n0)] = f2bf(acc[i][0][r] + bb0);
          smm[swz(m, n1)] = f2bf(acc[i][1][r] + bb1);
        }
    }
    __syncthreads();   // B3

    // ---- L3: c = silu(m @ Wc1 + bc1); partial w = c . Wc2 ----
    {
      f32x4 z = {0.f, 0.f, 0.f, 0.f};
      acc[0][0] = z; acc[0][1] = z; acc[1][0] = z; acc[1][1] = z;
    }
    gemm128(smm, sW3, rA, rB, k0l, acc);
    {
      const float bb0 = sb[256 + n0], bb1 = sb[256 + n1];
      const float c0 = sb[384 + n0], c1 = sb[384 + n1];
#pragma unroll
      for (int i = 0; i < 2; ++i)
#pragma unroll
        for (int r = 0; r < 4; ++r) {
          float pw = silu_f(acc[i][0][r] + bb0) * c0 + silu_f(acc[i][1][r] + bb1) * c1;
          pw += __shfl_xor(pw, 1);
          pw += __shfl_xor(pw, 2);
          pw += __shfl_xor(pw, 4);
          pw += __shfl_xor(pw, 8);
          if (l15 == 0) swpart[w & 3][rowbase + 16 * i + l4 * 4 + r] = pw;
        }
    }

    // ---- agg run-reduction: thread (col=tid&127, quarter=tid>>7) scans 16 rows ----
    {
      const int c = tid & 127;
      int r = (tid >> 7) * 16;
      int cur = sdst[p][r];
      float accs = 0.f;
#pragma unroll 4
      for (int k = 0; k < 16; ++k, ++r) {
        const int d2 = sdst[p][r];
        if (d2 != cur) {   // uniform per wave (all lanes share quarter)
          unsafeAtomicAdd(agg + ((size_t)(b * N_ + cur)) * H_ + c, accs);
          accs = 0.f;
          cur = d2;
        }
        accs += bf2f(smm[swz(r, c)]);
      }
      unsafeAtomicAdd(agg + ((size_t)(b * N_ + cur)) * H_ + c, accs);
    }
    __syncthreads();   // B4

    // ---- coord scatter: segmented scan over sorted dst (wave 0) ----
    if (tid < 64) {
      float wc = bc2v;
#pragma unroll
      for (int cg = 0; cg < 4; ++cg) wc += swpart[cg][tid];
      const float4 g = sgeo[p][tid];
      const float inv = 1.0f / (g.w + 1e-8f);
      float vx = wc * g.x * inv, vy = wc * g.y * inv, vz = wc * g.z * inv;
      const int myd = sdst[p][tid];
      int flg = (tid == 0) || (sdst[p][(tid + 63) & 63] != myd) ? 1 : 0;
      if (tid == 0) flg = 1;
#pragma unroll
      for (int off = 1; off < 64; off <<= 1) {
        float ux = __shfl_up(vx, off);
        float uy = __shfl_up(vy, off);
        float uz = __shfl_up(vz, off);
        int uf = __shfl_up(flg, off);
        if (tid >= off) {
          if (!flg) { vx += ux; vy += uy; vz += uz; }
          flg |= uf;
        }
      }
      const bool tail = (tid == 63) || (sdst[p][(tid + 1) & 63] != myd);
      if (tail) {
        float* bp = cdelta + ((size_t)(b * N_ + myd)) * 3;
        unsafeAtomicAdd(bp + 0, vx);
        unsafeAtomicAdd(bp + 1, vy);
        unsafeAtomicAdd(bp + 2, vz);
      }
    }
    // no barrier: next gather writes smsg (last read pre-B2) and parity buffers
  }
}

// ---------------- node kernel (unchanged) ----------------
__device__ __forceinline__ float bfbits(u32 x) { return __uint_as_float(x); }

__global__ __launch_bounds__(512, 2) void egnn_node(
    const float* __restrict__ nf, const float* __restrict__ coords,
    const float* __restrict__ agg, const float* __restrict__ cdelta,
    const float* __restrict__ Wn1, const float* __restrict__ bn1,
    const float* __restrict__ Wn2, const float* __restrict__ bn2,
    float* __restrict__ out_nf, float* __restrict__ out_c)
{
  __shared__ unsigned short sWn1[192 * H_];
  __shared__ unsigned short sWn2[H_ * D_];
  __shared__ float sb[192];
  __shared__ float swork[8][328];

  const int tid = threadIdx.x;
  for (int i = tid; i < 192 * H_; i += 512) sWn1[i] = f2bf(Wn1[i]);
  for (int i = tid; i < H_ * D_; i += 512) sWn2[i] = f2bf(Wn2[i]);
  if (tid < 128) sb[tid] = bn1[tid];
  if (tid >= 128 && tid < 192) sb[tid] = bn2[tid - 128];
  __syncthreads();

  const int wave = tid >> 6;
  const int lane = tid & 63;
  float* W = swork[wave];

  const int total = B_ * N_;
  const int stride = gridDim.x * 8;

  for (int task = blockIdx.x * 8 + wave; task < total; task += stride) {
    const float* nfp = nf + (size_t)task * D_;
    const float* ap = agg + (size_t)task * H_;
    W[lane] = nfp[lane];
    W[64 + lane] = ap[lane];
    W[128 + lane] = ap[64 + lane];
    __syncthreads();

    {
      const unsigned short* wp = sWn1 + 2 * lane;
      float a0 = 0.f, a1 = 0.f, a2 = 0.f, a3 = 0.f;
#pragma unroll 8
      for (int k = 0; k < 192; k += 2) {
        float2 x = *(const float2*)&W[k];
        u32 p0 = *(const u32*)(wp + k * H_);
        u32 p1 = *(const u32*)(wp + (k + 1) * H_);
        a0 = fmaf(x.x, bfbits(p0 << 16), a0);
        a1 = fmaf(x.x, bfbits(p0 & 0xffff0000u), a1);
        a2 = fmaf(x.y, bfbits(p1 << 16), a2);
        a3 = fmaf(x.y, bfbits(p1 & 0xffff0000u), a3);
      }
      float h0 = silu_f(a0 + a2 + sb[2 * lane]);
      float h1 = silu_f(a1 + a3 + sb[2 * lane + 1]);
      ((float2*)(W + 192))[lane] = make_float2(h0, h1);
    }
    __syncthreads();

    {
      float a0 = 0.f, a1 = 0.f, a2 = 0.f, a3 = 0.f;
#pragma unroll 8
      for (int k = 0; k < 128; k += 4) {
        float2 xa = *(const float2*)&W[192 + k];
        float2 xb = *(const float2*)&W[192 + k + 2];
        a0 = fmaf(xa.x, bfbits(((u32)sWn2[(k + 0) * D_ + lane]) << 16), a0);
        a1 = fmaf(xa.y, bfbits(((u32)sWn2[(k + 1) * D_ + lane]) << 16), a1);
        a2 = fmaf(xb.x, bfbits(((u32)sWn2[(k + 2) * D_ + lane]) << 16), a2);
        a3 = fmaf(xb.y, bfbits(((u32)sWn2[(k + 3) * D_ + lane]) << 16), a3);
      }
      out_nf[(size_t)task * D_ + lane] =
          nfp[lane] + (a0 + a1 + a2 + a3) + sb[128 + lane];
      if (lane < 3) {
        out_c[(size_t)task * 3 + lane] =
            coords[(size_t)task * 3 + lane] + cdelta[(size_t)task * 3 + lane];
      }
    }
    __syncthreads();
  }
}

extern "C" void kernel_launch(void* const* d_in, const int* in_sizes, int n_in,
                              void* d_out, int out_size, void* d_ws, size_t ws_size,
                              hipStream_t stream) {
  const float* nf     = (const float*)d_in[0];
  const float* coords = (const float*)d_in[1];
  const int*   ei     = (const int*)d_in[2];
  const float* Wm1 = (const float*)d_in[3];
  const float* bm1 = (const float*)d_in[4];
  const float* Wm2 = (const float*)d_in[5];
  const float* bm2 = (const float*)d_in[6];
  const float* Wn1 = (const float*)d_in[7];
  const float* bn1 = (const float*)d_in[8];
  const float* Wn2 = (const float*)d_in[9];
  const float* bn2 = (const float*)d_in[10];
  const float* Wc1 = (const float*)d_in[11];
  const float* bc1 = (const float*)d_in[12];
  const float* Wc2 = (const float*)d_in[13];
  const float* bc2 = (const float*)d_in[14];

  // workspace layout (floats): agg | cdelta | hist(int 4096) | src_s | dst_s
  float* agg    = (float*)d_ws;                               // 4,194,304 f
  float* cdelta = agg + (size_t)B_ * N_ * H_;                 //    98,304 f
  int*   hist   = (int*)(cdelta + (size_t)B_ * N_ * 3);       //     4,096 i
  int*   src_s  = hist + 4096;                                //   131,072 i
  int*   dst_s  = src_s + E_;                                 //   131,072 i

  float* out_nf = (float*)d_out;
  float* out_c  = out_nf + (size_t)B_ * N_ * D_;

  const size_t zero_bytes =
      ((size_t)B_ * N_ * H_ + (size_t)B_ * N_ * 3 + 4096) * sizeof(float);
  hipMemsetAsync(d_ws, 0, zero_bytes, stream);

  hist_k<<<E_ / 256, 256, 0, stream>>>(ei, hist);
  scan4096<<<1, 1024, 0, stream>>>(hist);
  scatter_k<<<E_ / 256, 256, 0, stream>>>(ei, hist, src_s, dst_s);

  egnn_edge_mfma<<<EDGE_BLOCKS, 512, 0, stream>>>(
      nf, coords, src_s, dst_s, Wm1, bm1, Wm2, bm2, Wc1, bc1, Wc2, bc2,
      agg, cdelta);
  egnn_node<<<512, 512, 0, stream>>>(nf, coords, agg, cdelta,
                                     Wn1, bn1, Wn2, bn2, out_nf, out_c);
}

// Round 4
// 455.958 us; speedup vs baseline: 9.1376x; 1.3021x over previous
//
#include <hip/hip_runtime.h>
#include <hip/hip_bf16.h>

#define B_ 8
#define N_ 4096
#define E_ 131072
#define D_ 64
#define H_ 128

#define EDGE_BLOCKS 256
#define ETILE 128
#define TILES_TOTAL ((B_ * E_) / ETILE)               // 8192 tiles of 128 edges
#define TILES_PER_BLOCK (TILES_TOTAL / EDGE_BLOCKS)   // 32

typedef unsigned int u32;
typedef short bf16x8 __attribute__((ext_vector_type(8)));
typedef float f32x4 __attribute__((ext_vector_type(4)));

__device__ __forceinline__ unsigned short f2bf(float f) {
  u32 x = __float_as_uint(f);
  x += 0x7fffu + ((x >> 16) & 1u);   // RNE
  return (unsigned short)(x >> 16);
}
__device__ __forceinline__ float bf2f(unsigned short v) {
  return __uint_as_float(((u32)v) << 16);
}
__device__ __forceinline__ float silu_f(float x) { return x / (1.0f + __expf(-x)); }

// XOR-swizzled u16 index into a [rows][128] bf16 LDS tile (row stride 256 B).
__device__ __forceinline__ int swz(int row, int col) {
  return row * 128 + (col ^ ((row & 7) << 3));
}

__device__ __forceinline__ void gemm128(const unsigned short* in,
                                        const unsigned short* wT,
                                        int rA, int rB, int k0l, f32x4 acc[2][2]) {
#pragma unroll
  for (int ks = 0; ks < 4; ++ks) {
    const int k = ks * 32 + k0l;
    bf16x8 a0 = *(const bf16x8*)&in[swz(rA, k)];
    bf16x8 a1 = *(const bf16x8*)&in[swz(rA + 16, k)];
    bf16x8 b0 = *(const bf16x8*)&wT[swz(rB, k)];
    bf16x8 b1 = *(const bf16x8*)&wT[swz(rB + 16, k)];
    acc[0][0] = __builtin_amdgcn_mfma_f32_16x16x32_bf16(a0, b0, acc[0][0], 0, 0, 0);
    acc[0][1] = __builtin_amdgcn_mfma_f32_16x16x32_bf16(a0, b1, acc[0][1], 0, 0, 0);
    acc[1][0] = __builtin_amdgcn_mfma_f32_16x16x32_bf16(a1, b0, acc[1][0], 0, 0, 0);
    acc[1][1] = __builtin_amdgcn_mfma_f32_16x16x32_bf16(a1, b1, acc[1][1], 0, 0, 0);
  }
}

// ---------------- prep kernels ----------------
__global__ void nf2bf_k(const float* __restrict__ nf, unsigned short* __restrict__ nf16) {
  const int i = blockIdx.x * 256 + threadIdx.x;   // over B*N*64/4 uint2 outputs
  float4 v = ((const float4*)nf)[i];
  u32 p0 = (u32)f2bf(v.x) | ((u32)f2bf(v.y) << 16);
  u32 p1 = (u32)f2bf(v.z) | ((u32)f2bf(v.w) << 16);
  ((uint2*)nf16)[i] = make_uint2(p0, p1);
}

__global__ void hist_k(const int* __restrict__ ei, int* __restrict__ hist) {
  const int e = blockIdx.x * 256 + threadIdx.x;
  atomicAdd(&hist[ei[E_ + e]], 1);
}

__global__ __launch_bounds__(1024) void scan4096(int* __restrict__ h) {
  __shared__ int wsums[16];
  const int tid = threadIdx.x;
  const int lane = tid & 63, wv = tid >> 6;
  int4 v = ((int4*)h)[tid];
  const int s = v.x + v.y + v.z + v.w;
  int incl = s;
#pragma unroll
  for (int off = 1; off < 64; off <<= 1) {
    int u = __shfl_up(incl, off);
    if (lane >= off) incl += u;
  }
  if (lane == 63) wsums[wv] = incl;
  __syncthreads();
  if (wv == 0) {
    int ws = (lane < 16) ? wsums[lane] : 0;
#pragma unroll
    for (int off = 1; off < 16; off <<= 1) {
      int u = __shfl_up(ws, off);
      if (lane >= off) ws += u;
    }
    if (lane < 16) wsums[lane] = ws;
  }
  __syncthreads();
  int base = (wv ? wsums[wv - 1] : 0) + (incl - s);
  int4 o;
  o.x = base; o.y = base + v.x; o.z = o.y + v.y; o.w = o.z + v.z;
  ((int4*)h)[tid] = o;
}

__global__ void scatter_k(const int* __restrict__ ei, int* __restrict__ offs,
                          int* __restrict__ src_s, int* __restrict__ dst_s) {
  const int e = blockIdx.x * 256 + threadIdx.x;
  const int d = ei[E_ + e];
  const int p = atomicAdd(&offs[d], 1);
  src_s[p] = ei[e];
  dst_s[p] = d;
}

// ---------------- edge kernel: 1024 thr, 128-edge tiles, 1 act buffer ----------------
__global__ __launch_bounds__(1024, 4) void egnn_edge_mfma(
    const unsigned short* __restrict__ nf16, const float* __restrict__ coords,
    const int* __restrict__ src_s, const int* __restrict__ dst_s,
    const float* __restrict__ Wm1, const float* __restrict__ bm1,
    const float* __restrict__ Wm2, const float* __restrict__ bm2,
    const float* __restrict__ Wc1, const float* __restrict__ bc1,
    const float* __restrict__ Wc2, const float* __restrict__ bc2,
    float* __restrict__ agg, float* __restrict__ cdelta)
{
  __shared__ unsigned short sW1[128 * 128];       // 32 KB each
  __shared__ unsigned short sW2[128 * 128];
  __shared__ unsigned short sW3[128 * 128];
  __shared__ unsigned short buf[ETILE * 128];     // msg -> h -> m (reused)
  __shared__ float4 sgeo[2][ETILE];
  __shared__ int sdst[2][ETILE];
  __shared__ float swpart[4][ETILE];

  const int tid = threadIdx.x;
  for (int i = tid; i < 128 * 128; i += 1024) {
    const int k = i >> 7, n = i & 127;
    const int d = swz(n, k);
    sW1[d] = f2bf(Wm1[i]);
    sW2[d] = f2bf(Wm2[i]);
    sW3[d] = f2bf(Wc1[i]);
  }

  const int lane = tid & 63;
  const int w = tid >> 6;
  const int l15 = lane & 15;
  const int l4 = lane >> 4;
  const int k0l = l4 * 8;
  const int rowbase = (w >> 2) * 32;   // {0,32,64,96}
  const int colbase = (w & 3) * 32;
  const int rA = rowbase + l15;
  const int rB = colbase + l15;
  const int n0 = colbase + l15;
  const int n1 = n0 + 16;

  // per-thread constants (n0/n1 fixed) -> registers, no LDS
  const float bb1_0 = bm1[n0], bb1_1 = bm1[n1];
  const float bb2_0 = bm2[n0], bb2_1 = bm2[n1];
  const float bb3_0 = bc1[n0], bb3_1 = bc1[n1];
  const float wc2_0 = Wc2[n0], wc2_1 = Wc2[n1];
  const float wr_0 = Wm1[128 * 128 + n0], wr_1 = Wm1[128 * 128 + n1];
  const float bc2v = bc2[0];

  const int m_t = tid >> 3;   // gather: 8 threads per edge row
  const int q_t = tid & 7;

  // XCD swizzle: batch b owned by one XCD (nf16 slice L2-resident)
  const int myblk = (blockIdx.x & 7) * (EDGE_BLOCKS / 8) + (blockIdx.x >> 3);
  const int b = myblk >> 5;                     // 32 blocks per batch
  const int gbase = (myblk & 31) * TILES_PER_BLOCK;

  __syncthreads();

  for (int t = 0; t < TILES_PER_BLOCK; ++t) {
    const int p = t & 1;
    const int ebase = (gbase + t) * ETILE;

    // ---- gather (bf16 direct copy) + geometry ----
    if (tid < ETILE) {
      const int e = ebase + tid;
      const int s = src_s[e];
      const int d = dst_s[e];
      sdst[p][tid] = d;
      const float* cs = coords + (size_t)(b * N_ + s) * 3;
      const float* cd = coords + (size_t)(b * N_ + d) * 3;
      const float d0 = cd[0] - cs[0], d1 = cd[1] - cs[1], d2 = cd[2] - cs[2];
      const float dist = sqrtf(fmaf(d0, d0, fmaf(d1, d1, d2 * d2)));
      sgeo[p][tid] = make_float4(d0, d1, d2, dist);
    }
    {
      const int e = ebase + m_t;
      const int s = src_s[e];
      const int d = dst_s[e];
      const uint4* ps = (const uint4*)(nf16 + (size_t)(b * N_ + s) * 64);
      const uint4* pd = (const uint4*)(nf16 + (size_t)(b * N_ + d) * 64);
      uint4 vs = ps[q_t];
      uint4 vd = pd[q_t];
      *(uint4*)&buf[swz(m_t, q_t * 8)] = vs;        // granule-aligned, conflict-free
      *(uint4*)&buf[swz(m_t, 64 + q_t * 8)] = vd;
    }
    __syncthreads();   // B1

    // ---- L1: h = silu(msg @ Wm1 + bm1 + dist * Wm1[128,:]) ----
    f32x4 acc[2][2];
    {
      f32x4 z = {0.f, 0.f, 0.f, 0.f};
      acc[0][0] = z; acc[0][1] = z; acc[1][0] = z; acc[1][1] = z;
    }
    gemm128(buf, sW1, rA, rB, k0l, acc);
    float hv[2][2][4];
#pragma unroll
    for (int i = 0; i < 2; ++i)
#pragma unroll
      for (int r = 0; r < 4; ++r) {
        const int m = rowbase + 16 * i + l4 * 4 + r;
        const float dist = sgeo[p][m].w;
        hv[i][0][r] = silu_f(acc[i][0][r] + bb1_0 + dist * wr_0);
        hv[i][1][r] = silu_f(acc[i][1][r] + bb1_1 + dist * wr_1);
      }
    __syncthreads();   // B2 (all msg reads done)
#pragma unroll
    for (int i = 0; i < 2; ++i)
#pragma unroll
      for (int r = 0; r < 4; ++r) {
        const int m = rowbase + 16 * i + l4 * 4 + r;
        buf[swz(m, n0)] = f2bf(hv[i][0][r]);
        buf[swz(m, n1)] = f2bf(hv[i][1][r]);
      }
    __syncthreads();   // B3 (h visible)

    // ---- L2: m = h @ Wm2 + bm2 ----
    {
      f32x4 z = {0.f, 0.f, 0.f, 0.f};
      acc[0][0] = z; acc[0][1] = z; acc[1][0] = z; acc[1][1] = z;
    }
    gemm128(buf, sW2, rA, rB, k0l, acc);
    float mv0[2][4], mv1[2][4];
#pragma unroll
    for (int i = 0; i < 2; ++i)
#pragma unroll
      for (int r = 0; r < 4; ++r) {
        mv0[i][r] = acc[i][0][r] + bb2_0;
        mv1[i][r] = acc[i][1][r] + bb2_1;
      }
    __syncthreads();   // B4 (all h reads done)
#pragma unroll
    for (int i = 0; i < 2; ++i)
#pragma unroll
      for (int r = 0; r < 4; ++r) {
        const int m = rowbase + 16 * i + l4 * 4 + r;
        buf[swz(m, n0)] = f2bf(mv0[i][r]);
        buf[swz(m, n1)] = f2bf(mv1[i][r]);
      }
    __syncthreads();   // B5 (m visible)

    // ---- L3: c = silu(m @ Wc1 + bc1); partial w = c . Wc2 ----
    {
      f32x4 z = {0.f, 0.f, 0.f, 0.f};
      acc[0][0] = z; acc[0][1] = z; acc[1][0] = z; acc[1][1] = z;
    }
    gemm128(buf, sW3, rA, rB, k0l, acc);
#pragma unroll
    for (int i = 0; i < 2; ++i)
#pragma unroll
      for (int r = 0; r < 4; ++r) {
        float pw = silu_f(acc[i][0][r] + bb3_0) * wc2_0 +
                   silu_f(acc[i][1][r] + bb3_1) * wc2_1;
        pw += __shfl_xor(pw, 1);
        pw += __shfl_xor(pw, 2);
        pw += __shfl_xor(pw, 4);
        pw += __shfl_xor(pw, 8);
        if (l15 == 0) swpart[w & 3][rowbase + 16 * i + l4 * 4 + r] = pw;
      }

    // ---- agg run-reduction: thread (col=tid&127, group=tid>>7) scans 16 rows ----
    {
      const int c = tid & 127;
      int r = (tid >> 7) * 16;
      int cur = sdst[p][r];
      float accs = 0.f;
#pragma unroll 4
      for (int k = 0; k < 16; ++k, ++r) {
        const int d2 = sdst[p][r];
        if (d2 != cur) {   // uniform per wave (group constant across a wave)
          unsafeAtomicAdd(agg + ((size_t)(b * N_ + cur)) * H_ + c, accs);
          accs = 0.f;
          cur = d2;
        }
        accs += bf2f(buf[swz(r, c)]);
      }
      unsafeAtomicAdd(agg + ((size_t)(b * N_ + cur)) * H_ + c, accs);
    }
    __syncthreads();   // B6 (buf free, swpart ready)

    // ---- coord scatter: segmented scan over 128 sorted rows (waves 0,1) ----
    if (tid < ETILE) {
      float wc = bc2v;
#pragma unroll
      for (int cg = 0; cg < 4; ++cg) wc += swpart[cg][tid];
      const float4 g = sgeo[p][tid];
      const float inv = 1.0f / (g.w + 1e-8f);
      float vx = wc * g.x * inv, vy = wc * g.y * inv, vz = wc * g.z * inv;
      const int myd = sdst[p][tid];
      int flg = (lane == 0) ? 1 : (sdst[p][tid - 1] != myd);
#pragma unroll
      for (int off = 1; off < 64; off <<= 1) {
        float ux = __shfl_up(vx, off);
        float uy = __shfl_up(vy, off);
        float uz = __shfl_up(vz, off);
        int uf = __shfl_up(flg, off);
        if (lane >= off) {
          if (!flg) { vx += ux; vy += uy; vz += uz; }
          flg |= uf;
        }
      }
      const bool tail = (lane == 63) || (sdst[p][tid + 1] != myd);
      if (tail) {
        float* bp = cdelta + ((size_t)(b * N_ + myd)) * 3;
        unsafeAtomicAdd(bp + 0, vx);
        unsafeAtomicAdd(bp + 1, vy);
        unsafeAtomicAdd(bp + 2, vz);
      }
    }
    // next gather overwrites buf (last read pre-B6) and parity p^1 buffers: safe
  }
}

// ---------------- node kernel (unchanged) ----------------
__device__ __forceinline__ float bfbits(u32 x) { return __uint_as_float(x); }

__global__ __launch_bounds__(512, 2) void egnn_node(
    const float* __restrict__ nf, const float* __restrict__ coords,
    const float* __restrict__ agg, const float* __restrict__ cdelta,
    const float* __restrict__ Wn1, const float* __restrict__ bn1,
    const float* __restrict__ Wn2, const float* __restrict__ bn2,
    float* __restrict__ out_nf, float* __restrict__ out_c)
{
  __shared__ unsigned short sWn1[192 * H_];
  __shared__ unsigned short sWn2[H_ * D_];
  __shared__ float sb[192];
  __shared__ float swork[8][328];

  const int tid = threadIdx.x;
  for (int i = tid; i < 192 * H_; i += 512) sWn1[i] = f2bf(Wn1[i]);
  for (int i = tid; i < H_ * D_; i += 512) sWn2[i] = f2bf(Wn2[i]);
  if (tid < 128) sb[tid] = bn1[tid];
  if (tid >= 128 && tid < 192) sb[tid] = bn2[tid - 128];
  __syncthreads();

  const int wave = tid >> 6;
  const int lane = tid & 63;
  float* W = swork[wave];

  const int total = B_ * N_;
  const int stride = gridDim.x * 8;

  for (int task = blockIdx.x * 8 + wave; task < total; task += stride) {
    const float* nfp = nf + (size_t)task * D_;
    const float* ap = agg + (size_t)task * H_;
    W[lane] = nfp[lane];
    W[64 + lane] = ap[lane];
    W[128 + lane] = ap[64 + lane];
    __syncthreads();

    {
      const unsigned short* wp = sWn1 + 2 * lane;
      float a0 = 0.f, a1 = 0.f, a2 = 0.f, a3 = 0.f;
#pragma unroll 8
      for (int k = 0; k < 192; k += 2) {
        float2 x = *(const float2*)&W[k];
        u32 p0 = *(const u32*)(wp + k * H_);
        u32 p1 = *(const u32*)(wp + (k + 1) * H_);
        a0 = fmaf(x.x, bfbits(p0 << 16), a0);
        a1 = fmaf(x.x, bfbits(p0 & 0xffff0000u), a1);
        a2 = fmaf(x.y, bfbits(p1 << 16), a2);
        a3 = fmaf(x.y, bfbits(p1 & 0xffff0000u), a3);
      }
      float h0 = silu_f(a0 + a2 + sb[2 * lane]);
      float h1 = silu_f(a1 + a3 + sb[2 * lane + 1]);
      ((float2*)(W + 192))[lane] = make_float2(h0, h1);
    }
    __syncthreads();

    {
      float a0 = 0.f, a1 = 0.f, a2 = 0.f, a3 = 0.f;
#pragma unroll 8
      for (int k = 0; k < 128; k += 4) {
        float2 xa = *(const float2*)&W[192 + k];
        float2 xb = *(const float2*)&W[192 + k + 2];
        a0 = fmaf(xa.x, bfbits(((u32)sWn2[(k + 0) * D_ + lane]) << 16), a0);
        a1 = fmaf(xa.y, bfbits(((u32)sWn2[(k + 1) * D_ + lane]) << 16), a1);
        a2 = fmaf(xb.x, bfbits(((u32)sWn2[(k + 2) * D_ + lane]) << 16), a2);
        a3 = fmaf(xb.y, bfbits(((u32)sWn2[(k + 3) * D_ + lane]) << 16), a3);
      }
      out_nf[(size_t)task * D_ + lane] =
          nfp[lane] + (a0 + a1 + a2 + a3) + sb[128 + lane];
      if (lane < 3) {
        out_c[(size_t)task * 3 + lane] =
            coords[(size_t)task * 3 + lane] + cdelta[(size_t)task * 3 + lane];
      }
    }
    __syncthreads();
  }
}

extern "C" void kernel_launch(void* const* d_in, const int* in_sizes, int n_in,
                              void* d_out, int out_size, void* d_ws, size_t ws_size,
                              hipStream_t stream) {
  const float* nf     = (const float*)d_in[0];
  const float* coords = (const float*)d_in[1];
  const int*   ei     = (const int*)d_in[2];
  const float* Wm1 = (const float*)d_in[3];
  const float* bm1 = (const float*)d_in[4];
  const float* Wm2 = (const float*)d_in[5];
  const float* bm2 = (const float*)d_in[6];
  const float* Wn1 = (const float*)d_in[7];
  const float* bn1 = (const float*)d_in[8];
  const float* Wn2 = (const float*)d_in[9];
  const float* bn2 = (const float*)d_in[10];
  const float* Wc1 = (const float*)d_in[11];
  const float* bc1 = (const float*)d_in[12];
  const float* Wc2 = (const float*)d_in[13];
  const float* bc2 = (const float*)d_in[14];

  // workspace (floats): agg | cdelta | hist(4096 i) | src_s | dst_s
  float* agg    = (float*)d_ws;                               // 4,194,304 f
  float* cdelta = agg + (size_t)B_ * N_ * H_;                 //    98,304 f
  int*   hist   = (int*)(cdelta + (size_t)B_ * N_ * 3);       //     4,096 i
  int*   src_s  = hist + 4096;                                //   131,072 i
  int*   dst_s  = src_s + E_;                                 //   131,072 i

  float* out_nf = (float*)d_out;
  float* out_c  = out_nf + (size_t)B_ * N_ * D_;

  // nf16 scratch lives in d_out's head (4 MB); node kernel fully overwrites
  // d_out afterwards, so this is safe and deterministic.
  unsigned short* nf16 = (unsigned short*)d_out;

  const size_t zero_bytes =
      ((size_t)B_ * N_ * H_ + (size_t)B_ * N_ * 3 + 4096) * sizeof(float);
  hipMemsetAsync(d_ws, 0, zero_bytes, stream);

  nf2bf_k<<<(B_ * N_ * D_ / 4) / 256, 256, 0, stream>>>(nf, nf16);
  hist_k<<<E_ / 256, 256, 0, stream>>>(ei, hist);
  scan4096<<<1, 1024, 0, stream>>>(hist);
  scatter_k<<<E_ / 256, 256, 0, stream>>>(ei, hist, src_s, dst_s);

  egnn_edge_mfma<<<EDGE_BLOCKS, 1024, 0, stream>>>(
      nf16, coords, src_s, dst_s, Wm1, bm1, Wm2, bm2, Wc1, bc1, Wc2, bc2,
      agg, cdelta);
  egnn_node<<<512, 512, 0, stream>>>(nf, coords, agg, cdelta,
                                     Wn1, bn1, Wn2, bn2, out_nf, out_c);
}